// Round 3
// baseline (22.441 us; speedup 1.0000x reference)
//
#include <hip/hip_runtime.h>
#include <math.h>

// Problem constants (from reference): N=32, CI=32, CO=32, H=64, W=64, K=2
#define NN 32
#define CI 32
#define CO 32
#define HH 64
#define WW 64

#define G    8            // co's per thread
#define COG  (CO / G)     // 4 co-groups
#define NXCD 8

typedef float v2f __attribute__((ext_vector_type(2)));   // native vec for NT stores

// ---------------------------------------------------------------------------
// Kernel 1: W[co][ci][par] = softmax over ci of logits[co][ci][k1][k2]
// (par = k1*2 + k2 = flattened last two dims). 128 softmaxes over 32 values.
// ---------------------------------------------------------------------------
__global__ void sumconv_weights(const float* __restrict__ logits,
                                float* __restrict__ Wout) {
    int t = threadIdx.x;            // 0..127
    if (t >= CO * 4) return;
    int co  = t >> 2;
    int par = t & 3;
    const float* base = logits + co * CI * 4 + par;

    float m = -1e30f;
#pragma unroll
    for (int ci = 0; ci < CI; ++ci) m = fmaxf(m, base[ci * 4]);

    float e[CI];
    float s = 0.0f;
#pragma unroll
    for (int ci = 0; ci < CI; ++ci) {
        e[ci] = __expf(base[ci * 4] - m);
        s += e[ci];
    }
    float inv = 1.0f / s;
#pragma unroll
    for (int ci = 0; ci < CI; ++ci)
        Wout[co * CI * 4 + ci * 4 + par] = e[ci] * inv;
}

// ---------------------------------------------------------------------------
// Kernel 2: out[n,co,h,w] = log( sum_ci W[co,ci,par(h,w)] * exp(x[n,ci,h,w]) )
//
// Thread owns a 2x2 pixel quad -> all 4 parities in-thread -> weight read
// W[co][ci] (float4 of parities) is wave-uniform -> s_load_dwordx4, no LDS.
//
// XCD swizzle: 512 blocks, xcd = b&7. Each XCD owns a contiguous 1/8 of
// pixel space (x slab = 2 MB, fits 4 MB private L2) for ALL 4 co-groups;
// all 64 blocks/XCD are co-resident (2 blk/CU, 8 waves/CU), so the 8x
// logical x traffic is L2-resident. Non-temporal out stores keep the slab
// from being evicted by the write stream.
// ---------------------------------------------------------------------------
__global__ __launch_bounds__(256) void sumconv_main(
        const float* __restrict__ x,
        const float* __restrict__ Wn,
        float* __restrict__ out) {
    const int b    = blockIdx.x;          // 0..511
    const int xcd  = b & (NXCD - 1);
    const int slot = b >> 3;              // 0..63
    const int pix_chunk = xcd * 16 + (slot & 15);   // 0..127
    const int cog       = slot >> 4;                // 0..3

    const int qid = pix_chunk * 256 + threadIdx.x;  // quad id, 0..32767
    const int n   = qid >> 10;                      // 1024 quads per image
    const int qq  = qid & 1023;
    const int h   = (qq >> 5) << 1;                 // even row
    const int w   = (qq & 31) << 1;                 // even col
    const int co_base = cog * G;

    const float4* __restrict__ Wv = (const float4*)Wn;  // [co][ci] -> 4 parities

    const float* xb = x + ((n * CI) * HH + h) * WW + w;

    float acc[4][G];
#pragma unroll
    for (int q = 0; q < 4; ++q)
#pragma unroll
        for (int j = 0; j < G; ++j) acc[q][j] = 0.0f;

    for (int ci = 0; ci < CI; ++ci) {
        const float2 v0 = *(const float2*)(xb + ci * HH * WW);
        const float2 v1 = *(const float2*)(xb + ci * HH * WW + WW);
        const float e00 = __expf(v0.x);
        const float e01 = __expf(v0.y);
        const float e10 = __expf(v1.x);
        const float e11 = __expf(v1.y);
#pragma unroll
        for (int j = 0; j < G; ++j) {
            const float4 wv = Wv[(co_base + j) * CI + ci];  // wave-uniform -> s_load
            acc[0][j] = fmaf(wv.x, e00, acc[0][j]);
            acc[1][j] = fmaf(wv.y, e01, acc[1][j]);
            acc[2][j] = fmaf(wv.z, e10, acc[2][j]);
            acc[3][j] = fmaf(wv.w, e11, acc[3][j]);
        }
    }

#pragma unroll
    for (int j = 0; j < G; ++j) {
        const int co = co_base + j;
        float* ob = out + ((n * CO + co) * HH + h) * WW + w;
        v2f r0, r1;
        r0.x = __logf(acc[0][j]);
        r0.y = __logf(acc[1][j]);
        r1.x = __logf(acc[2][j]);
        r1.y = __logf(acc[3][j]);
        __builtin_nontemporal_store(r0, (v2f*)ob);
        __builtin_nontemporal_store(r1, (v2f*)(ob + WW));
    }
}

extern "C" void kernel_launch(void* const* d_in, const int* in_sizes, int n_in,
                              void* d_out, int out_size, void* d_ws, size_t ws_size,
                              hipStream_t stream) {
    const float* x      = (const float*)d_in[0];
    const float* logits = (const float*)d_in[1];
    float* out = (float*)d_out;
    float* Wn  = (float*)d_ws;   // 32*32*4 floats = 16 KB scratch

    sumconv_weights<<<1, 128, 0, stream>>>(logits, Wn);

    sumconv_main<<<NN * (HH / 2) * (WW / 2) * COG / 256, 256, 0, stream>>>(x, Wn, out);
}

// Round 4
// 18.820 us; speedup vs baseline: 1.1924x; 1.1924x over previous
//
#include <hip/hip_runtime.h>
#include <math.h>

// Problem constants (from reference): N=32, CI=32, CO=32, H=64, W=64, K=2
#define NN 32
#define CI 32
#define CO 32
#define HH 64
#define WW 64

#define G    8            // co's per thread/block
#define COG  (CO / G)     // 4 co-groups
#define NXCD 8

typedef float v2f __attribute__((ext_vector_type(2)));   // native vec for NT stores

// ---------------------------------------------------------------------------
// Single fused kernel.
//
// out[n,co,h,w] = log( sum_ci W[co,ci,par(h,w)] * exp(x[n,ci,h,w]) ),
//   W = softmax(logits over ci), par = (h&1)*2 + (w&1).
//
// Phase 0: each block computes softmax weights for its G=8 co's from logits
//          into LDS (G*CI float4 = 4 KB). 32 active threads, one (co,par)
//          softmax each. Replaces the serialized 1-block prologue kernel.
//
// Phase 1: thread owns a 2x2 pixel quad -> all 4 parities in-thread.
//          Weight reads are uniform-address ds_read_b128 broadcasts (free,
//          off the VMEM/L1 path) -- R3 post-mortem says the same-address
//          global_load_dwordx4 weight stream was the bottleneck.
//
// XCD swizzle: 512 blocks, xcd = b&7; each XCD owns a contiguous 1/8 of
// pixel space (2 MB x slab, L2-resident) for all 4 co-groups.
// ---------------------------------------------------------------------------
__global__ __launch_bounds__(256) void sumconv_fused(
        const float* __restrict__ x,
        const float* __restrict__ logits,
        float* __restrict__ out) {
    const int b    = blockIdx.x;          // 0..511
    const int xcd  = b & (NXCD - 1);
    const int slot = b >> 3;              // 0..63
    const int pix_chunk = xcd * 16 + (slot & 15);   // 0..127
    const int cog       = slot >> 4;                // 0..3
    const int co_base   = cog * G;

    __shared__ float4 WF[G * CI];         // [j][ci] -> float4 over parities

    // ---- Phase 0: per-block weight softmax (32 active threads) ----
    const int t = threadIdx.x;
    if (t < G * 4) {
        const int j   = t >> 2;           // local co
        const int par = t & 3;
        const float* base = logits + (co_base + j) * CI * 4 + par;

        float m = -1e30f;
#pragma unroll
        for (int ci = 0; ci < CI; ++ci) m = fmaxf(m, base[ci * 4]);

        float e[CI];
        float s = 0.0f;
#pragma unroll
        for (int ci = 0; ci < CI; ++ci) {
            e[ci] = __expf(base[ci * 4] - m);
            s += e[ci];
        }
        const float inv = 1.0f / s;
#pragma unroll
        for (int ci = 0; ci < CI; ++ci)
            ((float*)&WF[j * CI + ci])[par] = e[ci] * inv;
    }
    __syncthreads();

    // ---- Phase 1: main accumulation ----
    const int qid = pix_chunk * 256 + t;            // quad id, 0..32767
    const int n   = qid >> 10;                      // 1024 quads per image
    const int qq  = qid & 1023;
    const int h   = (qq >> 5) << 1;                 // even row
    const int w   = (qq & 31) << 1;                 // even col

    const float* xb = x + ((n * CI) * HH + h) * WW + w;

    float acc[4][G];
#pragma unroll
    for (int q = 0; q < 4; ++q)
#pragma unroll
        for (int j = 0; j < G; ++j) acc[q][j] = 0.0f;

#pragma unroll 4
    for (int ci = 0; ci < CI; ++ci) {
        const float2 v0 = *(const float2*)(xb + ci * HH * WW);
        const float2 v1 = *(const float2*)(xb + ci * HH * WW + WW);
        const float e00 = __expf(v0.x);
        const float e01 = __expf(v0.y);
        const float e10 = __expf(v1.x);
        const float e11 = __expf(v1.y);
#pragma unroll
        for (int j = 0; j < G; ++j) {
            const float4 wv = WF[j * CI + ci];      // uniform addr -> broadcast
            acc[0][j] = fmaf(wv.x, e00, acc[0][j]);
            acc[1][j] = fmaf(wv.y, e01, acc[1][j]);
            acc[2][j] = fmaf(wv.z, e10, acc[2][j]);
            acc[3][j] = fmaf(wv.w, e11, acc[3][j]);
        }
    }

#pragma unroll
    for (int j = 0; j < G; ++j) {
        const int co = co_base + j;
        float* ob = out + ((n * CO + co) * HH + h) * WW + w;
        v2f r0, r1;
        r0.x = __logf(acc[0][j]);
        r0.y = __logf(acc[1][j]);
        r1.x = __logf(acc[2][j]);
        r1.y = __logf(acc[3][j]);
        __builtin_nontemporal_store(r0, (v2f*)ob);
        __builtin_nontemporal_store(r1, (v2f*)(ob + WW));
    }
}

extern "C" void kernel_launch(void* const* d_in, const int* in_sizes, int n_in,
                              void* d_out, int out_size, void* d_ws, size_t ws_size,
                              hipStream_t stream) {
    const float* x      = (const float*)d_in[0];
    const float* logits = (const float*)d_in[1];
    float* out = (float*)d_out;

    sumconv_fused<<<NN * (HH / 2) * (WW / 2) * COG / 256, 256, 0, stream>>>(
        x, logits, out);
}